// Round 5
// baseline (272.563 us; speedup 1.0000x reference)
//
#include <hip/hip_runtime.h>
#include <hip/hip_bf16.h>

// CoordinateDescent: B=8, M=N=2048, R=32, f32 in/out.
// l1 = l2 = 0.01*0.5*2048 = 10.24 both factors.
#define L1REG 10.24f
#define L2REG 10.24f
#define KSPLIT 4

typedef float floatx4 __attribute__((ext_vector_type(4)));
typedef short shortx8 __attribute__((ext_vector_type(8)));

static __device__ __forceinline__ short f2b(float f) {
    __hip_bfloat16 h = __float2bfloat16(f);
    return (short)*reinterpret_cast<unsigned short*>(&h);
}

// Stage w rows [ks*512,+512) x 32 cols -> MFMA B-frag order (bf16) in bf[16384].
// Frag read: bf[(half)*8192 + s*512 + lane*8 + j] == B[n=lane&15][k=s*32+(lane>>4)*8+j].
static __device__ __forceinline__ void stage_w(const float* __restrict__ w, short* bf,
                                               int batch, int ks, int t) {
    const float* wsrc = w + ((size_t)batch * 2048 + ks * 512) * 32;
#pragma unroll
    for (int i = 0; i < 16; ++i) {
        int idx = t + i * 256;
        int k = idx >> 3;
        int rq = (idx & 7) * 4;
        float4 f = *(const float4*)(wsrc + (size_t)k * 32 + rq);
        int sbase = (k >> 5) * 512 + ((k >> 3) & 3) * 128 + (k & 7);
        float fv[4] = {f.x, f.y, f.z, f.w};
#pragma unroll
        for (int c = 0; c < 4; ++c) {
            int r = rq + c;
            bf[(r >> 4) * 8192 + sbase + (r & 15) * 8] = f2b(fv[c]);
        }
    }
}

// f32 b-partial over w rows [mblk*64,+64), by ks==0 blocks. pb[mblk][batch][32][32].
static __device__ __forceinline__ void b_partial(const float* __restrict__ w, float* pb,
                                                 int batch, int mblk, int t) {
    const float* wsl = w + ((size_t)batch * 2048 + mblk * 64) * 32;
    int ii = t >> 3, jq = (t & 7) * 4;
    float a0 = 0.f, a1 = 0.f, a2 = 0.f, a3 = 0.f;
#pragma unroll 8
    for (int n = 0; n < 64; ++n) {
        float wi = wsl[n * 32 + ii];
        float4 wj = *(const float4*)(wsl + n * 32 + jq);
        a0 = fmaf(wi, wj.x, a0);
        a1 = fmaf(wi, wj.y, a1);
        a2 = fmaf(wi, wj.z, a2);
        a3 = fmaf(wi, wj.w, a3);
    }
    float4 res = {a0, a1, a2, a3};
    *(float4*)(pb + ((size_t)mblk * 8 + batch) * 1024 + ii * 32 + jq) = res;
}

// ---- GEMM1: ap += x @ w slice; also emits xb (bf16 copy of x, [m][k]) ----
__global__ __launch_bounds__(256) void gemm1_kernel(const float* __restrict__ x,
                                                    const float* __restrict__ w,
                                                    float* __restrict__ ap,
                                                    float* __restrict__ pb,
                                                    short* __restrict__ xb) {
    __shared__ __align__(16) short bf[16384];
    int bz = blockIdx.x, t = threadIdx.x;
    int batch = bz >> 7, mblk = (bz >> 2) & 31, ks = bz & 3;
    stage_w(w, bf, batch, ks, t);
    __syncthreads();

    int lane = t & 63, wave = t >> 6;
    int b0off = lane * 8;
    int kq = (lane >> 4) * 8;
    size_t rowidx = (size_t)batch * 2048 + mblk * 64 + wave * 16 + (lane & 15);
    const float* xrow = x + rowidx * 2048 + ks * 512 + kq;
    short* xbrow = xb + rowidx * 2048 + ks * 512 + kq;

    floatx4 acc0 = {0.f, 0.f, 0.f, 0.f}, acc1 = {0.f, 0.f, 0.f, 0.f};
    float4 fa = *(const float4*)xrow;
    float4 fb = *(const float4*)(xrow + 4);
#pragma unroll
    for (int s = 0; s < 16; ++s) {
        float4 na = {0, 0, 0, 0}, nb = {0, 0, 0, 0};
        if (s < 15) {
            na = *(const float4*)(xrow + (s + 1) * 32);
            nb = *(const float4*)(xrow + (s + 1) * 32 + 4);
        }
        shortx8 af = {f2b(fa.x), f2b(fa.y), f2b(fa.z), f2b(fa.w),
                      f2b(fb.x), f2b(fb.y), f2b(fb.z), f2b(fb.w)};
        *(shortx8*)(xbrow + s * 32) = af;  // bf16 x side-product, coalesced 16B
        shortx8 b0 = *(const shortx8*)&bf[s * 512 + b0off];
        shortx8 b1 = *(const shortx8*)&bf[8192 + s * 512 + b0off];
        acc0 = __builtin_amdgcn_mfma_f32_16x16x32_bf16(af, b0, acc0, 0, 0, 0);
        acc1 = __builtin_amdgcn_mfma_f32_16x16x32_bf16(af, b1, acc1, 0, 0, 0);
        fa = na;
        fb = nb;
    }
    int orow = mblk * 64 + wave * 16 + (lane >> 4) * 4;
    float* ab = ap + (((size_t)ks * 8 + batch) * 2048 + orow) * 32 + (lane & 15);
#pragma unroll
    for (int i = 0; i < 4; ++i) {
        ab[i * 32] = acc0[i];
        ab[i * 32 + 16] = acc1[i];
    }
    if (ks == 0) b_partial(w, pb, batch, mblk, t);
}

// ---- GEMM2: ap += x^T @ w slice, reading bf16 xb; per-step wave-private transpose ----
__global__ __launch_bounds__(256) void gemm2_kernel(const short* __restrict__ xb,
                                                    const float* __restrict__ w,
                                                    float* __restrict__ ap,
                                                    float* __restrict__ pb) {
    __shared__ __align__(16) short bf[16384];
    __shared__ __align__(16) short xT[2048];
    int bz = blockIdx.x, t = threadIdx.x;
    int batch = bz >> 7, mblk = (bz >> 2) & 31, ks = bz & 3;
    stage_w(w, bf, batch, ks, t);
    __syncthreads();

    int lane = t & 63, wave = t >> 6;
    int b0off = lane * 8;
    short* xTw = &xT[wave * 512];
    int mloc = lane & 31;
    int ng = (lane >> 5) * 8;
    int n0w = mblk * 64 + wave * 16;
    const short* xp = xb + ((size_t)batch * 2048 + ks * 512 + mloc) * 2048 + n0w + ng;
    int rA = (lane & 15) * 32 + (lane >> 4) * 8;

    floatx4 acc0 = {0.f, 0.f, 0.f, 0.f}, acc1 = {0.f, 0.f, 0.f, 0.f};
    shortx8 fa = *(const shortx8*)xp;
#pragma unroll
    for (int s = 0; s < 16; ++s) {
#pragma unroll
        for (int j = 0; j < 8; ++j) xTw[(ng + j) * 32 + mloc] = fa[j];
        shortx8 na = {0, 0, 0, 0, 0, 0, 0, 0};
        if (s < 15) na = *(const shortx8*)(xp + (size_t)(s + 1) * 32 * 2048);
        shortx8 af = *(const shortx8*)&xTw[rA];  // wave-private, in-order DS: no barrier
        shortx8 b0 = *(const shortx8*)&bf[s * 512 + b0off];
        shortx8 b1 = *(const shortx8*)&bf[8192 + s * 512 + b0off];
        acc0 = __builtin_amdgcn_mfma_f32_16x16x32_bf16(af, b0, acc0, 0, 0, 0);
        acc1 = __builtin_amdgcn_mfma_f32_16x16x32_bf16(af, b1, acc1, 0, 0, 0);
        fa = na;
    }
    int orow = n0w + (lane >> 4) * 4;
    float* ab = ap + (((size_t)ks * 8 + batch) * 2048 + orow) * 32 + (lane & 15);
#pragma unroll
    for (int i = 0; i < 4; ++i) {
        ab[i * 32] = acc0[i];
        ab[i * 32 + 16] = acc1[i];
    }
    if (ks == 0) b_partial(w, pb, batch, mblk, t);
}

// ---- Gauss-Seidel: reduce partials, then sequential over r ----
__global__ __launch_bounds__(256) void gs_kernel(const float* __restrict__ win,
                                                 const float* __restrict__ ap,
                                                 const float* __restrict__ pb,
                                                 float* __restrict__ wout) {
    __shared__ float bs[1024];
    int bz = blockIdx.x, t = threadIdx.x;
    int batch = bz >> 3;
    int m = (bz & 7) * 256 + t;
    float4 bacc = {0.f, 0.f, 0.f, 0.f};
    const float* pbb = pb + (size_t)batch * 1024 + t * 4;
#pragma unroll 8
    for (int s = 0; s < 32; ++s) {
        float4 p = *(const float4*)(pbb + (size_t)s * 8192);
        bacc.x += p.x; bacc.y += p.y; bacc.z += p.z; bacc.w += p.w;
    }
    *(float4*)&bs[t * 4] = bacc;
    __syncthreads();

    float uv[32], av[32];
    const float* up = win + ((size_t)batch * 2048 + m) * 32;
#pragma unroll
    for (int q = 0; q < 8; ++q) *(float4*)&uv[q * 4] = *(const float4*)(up + q * 4);
#pragma unroll
    for (int q = 0; q < 8; ++q) {
        float4 sacc = {0.f, 0.f, 0.f, 0.f};
#pragma unroll
        for (int ks = 0; ks < KSPLIT; ++ks) {
            float4 p = *(const float4*)(ap + (((size_t)ks * 8 + batch) * 2048 + m) * 32 + q * 4);
            sacc.x += p.x; sacc.y += p.y; sacc.z += p.z; sacc.w += p.w;
        }
        *(float4*)&av[q * 4] = sacc;
    }
#pragma unroll
    for (int r = 0; r < 32; ++r) {
        float brr = bs[r * 32 + r];
        float t2 = -uv[r] * brr;
#pragma unroll
        for (int k = 0; k < 32; ++k) t2 = fmaf(uv[k], bs[r * 32 + k], t2);
        float num = av[r] - t2;
        float mag = fmaxf(fabsf(num) - L1REG, 0.f);
        num = copysignf(mag, num);
        uv[r] = (num + 1e-16f) / (brr + L2REG + 1e-16f);
    }
    float* op = wout + ((size_t)batch * 2048 + m) * 32;
#pragma unroll
    for (int q = 0; q < 8; ++q) *(float4*)(op + q * 4) = *(const float4*)&uv[q * 4];
}

extern "C" void kernel_launch(void* const* d_in, const int* in_sizes, int n_in,
                              void* d_out, int out_size, void* d_ws, size_t ws_size,
                              hipStream_t stream) {
    const float* x = (const float*)d_in[0];
    const float* u = (const float*)d_in[1];
    const float* v = (const float*)d_in[2];
    float* out_u = (float*)d_out;
    float* out_v = out_u + (size_t)8 * 2048 * 32;
    float* ap = (float*)d_ws;                          // [4][8][2048][32] f32 = 8 MB
    float* pb = ap + (size_t)KSPLIT * 8 * 2048 * 32;   // [32][8][32][32]  f32 = 1 MB
    short* xb = (short*)(pb + (size_t)32 * 8 * 1024);  // [8][2048][2048] bf16 = 67 MB

    // ---- factor 0: update u ----
    gemm1_kernel<<<1024, 256, 0, stream>>>(x, v, ap, pb, xb);   // a1 = x@v, b1, xb
    gs_kernel<<<64, 256, 0, stream>>>(u, ap, pb, out_u);        // u_new
    // ---- factor 1: update v ----
    gemm2_kernel<<<1024, 256, 0, stream>>>(xb, out_u, ap, pb);  // a2 = x^T@u_new, b2
    gs_kernel<<<64, 256, 0, stream>>>(v, ap, pb, out_v);        // v_new
}

// Round 6
// 266.969 us; speedup vs baseline: 1.0210x; 1.0210x over previous
//
#include <hip/hip_runtime.h>
#include <hip/hip_bf16.h>

// CoordinateDescent: B=8, M=N=2048, R=32, f32 in/out.
// l1 = l2 = 0.01*0.5*2048 = 10.24 both factors.
#define L1REG 10.24f
#define L2REG 10.24f
#define KSPLIT 4
#define PF 4  // prefetch depth (K-steps in flight)

typedef float floatx4 __attribute__((ext_vector_type(4)));
typedef short shortx8 __attribute__((ext_vector_type(8)));

static __device__ __forceinline__ short f2b(float f) {
    __hip_bfloat16 h = __float2bfloat16(f);
    return (short)*reinterpret_cast<unsigned short*>(&h);
}

// Stage w rows [ks*512,+512) x 32 cols -> MFMA B-frag order (bf16) in bf[16384].
// Frag read: bf[(half)*8192 + s*512 + lane*8 + j] == B[n=lane&15][k=s*32+(lane>>4)*8+j].
static __device__ __forceinline__ void stage_w(const float* __restrict__ w, short* bf,
                                               int batch, int ks, int t) {
    const float* wsrc = w + ((size_t)batch * 2048 + ks * 512) * 32;
#pragma unroll
    for (int i = 0; i < 16; ++i) {
        int idx = t + i * 256;
        int k = idx >> 3;
        int rq = (idx & 7) * 4;
        float4 f = *(const float4*)(wsrc + (size_t)k * 32 + rq);
        int sbase = (k >> 5) * 512 + ((k >> 3) & 3) * 128 + (k & 7);
        float fv[4] = {f.x, f.y, f.z, f.w};
#pragma unroll
        for (int c = 0; c < 4; ++c) {
            int r = rq + c;
            bf[(r >> 4) * 8192 + sbase + (r & 15) * 8] = f2b(fv[c]);
        }
    }
}

// f32 b-partial over w rows [mblk*64,+64), by ks==0 blocks. pb[mblk][batch][32][32].
static __device__ __forceinline__ void b_partial(const float* __restrict__ w, float* pb,
                                                 int batch, int mblk, int t) {
    const float* wsl = w + ((size_t)batch * 2048 + mblk * 64) * 32;
    int ii = t >> 3, jq = (t & 7) * 4;
    float a0 = 0.f, a1 = 0.f, a2 = 0.f, a3 = 0.f;
#pragma unroll 8
    for (int n = 0; n < 64; ++n) {
        float wi = wsl[n * 32 + ii];
        float4 wj = *(const float4*)(wsl + n * 32 + jq);
        a0 = fmaf(wi, wj.x, a0);
        a1 = fmaf(wi, wj.y, a1);
        a2 = fmaf(wi, wj.z, a2);
        a3 = fmaf(wi, wj.w, a3);
    }
    float4 res = {a0, a1, a2, a3};
    *(float4*)(pb + ((size_t)mblk * 8 + batch) * 1024 + ii * 32 + jq) = res;
}

// ---------------- GEMM (per block: 64 out rows x 32 cols, K-slice 512) ----------
//   TRANS=false: a += x[b,m,:] @ w   (a1 = x@v)     A direct from global rows
//   TRANS=true : a += x[b,:,n]^T @ w (a2 = x^T@u)   A via wave-private LDS transpose
// ap[ks][batch][row][32] plain-store partials; pb b-partials from ks==0 blocks.
template <bool TRANS>
__global__ __launch_bounds__(256, 4) void gemm_kernel(const float* __restrict__ x,
                                                      const float* __restrict__ w,
                                                      float* __restrict__ ap,
                                                      float* __restrict__ pb) {
    __shared__ __align__(16) short bf[16384];  // 32 KB packed B-frags
    __shared__ __align__(16) short xT[2048];   // 4 KB per-wave transpose tiles (TRANS)
    int bz = blockIdx.x, t = threadIdx.x;
    int batch = bz >> 7, mblk = (bz >> 2) & 31, ks = bz & 3;
    stage_w(w, bf, batch, ks, t);
    __syncthreads();

    int lane = t & 63, wave = t >> 6;
    int b0off = lane * 8;
    floatx4 acc0 = {0.f, 0.f, 0.f, 0.f}, acc1 = {0.f, 0.f, 0.f, 0.f};

    if (!TRANS) {
        int kq = (lane >> 4) * 8;
        const float* xrow =
            x + ((size_t)batch * 2048 + mblk * 64 + wave * 16 + (lane & 15)) * 2048 + ks * 512 + kq;
        float4 pfa[PF], pfb[PF];
#pragma unroll
        for (int p = 0; p < PF; ++p) {
            pfa[p] = *(const float4*)(xrow + p * 32);
            pfb[p] = *(const float4*)(xrow + p * 32 + 4);
        }
#pragma unroll
        for (int s = 0; s < 16; ++s) {
            float4 fa = pfa[s & (PF - 1)], fb = pfb[s & (PF - 1)];
            if (s + PF < 16) {
                pfa[s & (PF - 1)] = *(const float4*)(xrow + (s + PF) * 32);
                pfb[s & (PF - 1)] = *(const float4*)(xrow + (s + PF) * 32 + 4);
            }
            shortx8 af = {f2b(fa.x), f2b(fa.y), f2b(fa.z), f2b(fa.w),
                          f2b(fb.x), f2b(fb.y), f2b(fb.z), f2b(fb.w)};
            shortx8 b0 = *(const shortx8*)&bf[s * 512 + b0off];
            shortx8 b1 = *(const shortx8*)&bf[8192 + s * 512 + b0off];
            acc0 = __builtin_amdgcn_mfma_f32_16x16x32_bf16(af, b0, acc0, 0, 0, 0);
            acc1 = __builtin_amdgcn_mfma_f32_16x16x32_bf16(af, b1, acc1, 0, 0, 0);
        }
    } else {
        short* xTw = &xT[wave * 512];
        int mloc = lane & 31;
        int ng = (lane >> 5) * 8;
        int n0w = mblk * 64 + wave * 16;
        const float* xp = x + ((size_t)batch * 2048 + ks * 512 + mloc) * 2048 + n0w + ng;
        int rA = (lane & 15) * 32 + (lane >> 4) * 8;
        float4 pfa[PF], pfb[PF];
#pragma unroll
        for (int p = 0; p < PF; ++p) {
            pfa[p] = *(const float4*)(xp + (size_t)p * 32 * 2048);
            pfb[p] = *(const float4*)(xp + (size_t)p * 32 * 2048 + 4);
        }
#pragma unroll
        for (int s = 0; s < 16; ++s) {
            float4 fa = pfa[s & (PF - 1)], fb = pfb[s & (PF - 1)];
            if (s + PF < 16) {
                pfa[s & (PF - 1)] = *(const float4*)(xp + (size_t)(s + PF) * 32 * 2048);
                pfb[s & (PF - 1)] = *(const float4*)(xp + (size_t)(s + PF) * 32 * 2048 + 4);
            }
            xTw[(ng + 0) * 32 + mloc] = f2b(fa.x);
            xTw[(ng + 1) * 32 + mloc] = f2b(fa.y);
            xTw[(ng + 2) * 32 + mloc] = f2b(fa.z);
            xTw[(ng + 3) * 32 + mloc] = f2b(fa.w);
            xTw[(ng + 4) * 32 + mloc] = f2b(fb.x);
            xTw[(ng + 5) * 32 + mloc] = f2b(fb.y);
            xTw[(ng + 6) * 32 + mloc] = f2b(fb.z);
            xTw[(ng + 7) * 32 + mloc] = f2b(fb.w);
            shortx8 af = *(const shortx8*)&xTw[rA];  // wave-private, in-order DS
            shortx8 b0 = *(const shortx8*)&bf[s * 512 + b0off];
            shortx8 b1 = *(const shortx8*)&bf[8192 + s * 512 + b0off];
            acc0 = __builtin_amdgcn_mfma_f32_16x16x32_bf16(af, b0, acc0, 0, 0, 0);
            acc1 = __builtin_amdgcn_mfma_f32_16x16x32_bf16(af, b1, acc1, 0, 0, 0);
        }
    }
    // D: col = lane&15, row = (lane>>4)*4 + i ; plain stores (split-K regions disjoint)
    int orow = mblk * 64 + wave * 16 + (lane >> 4) * 4;
    float* ab = ap + (((size_t)ks * 8 + batch) * 2048 + orow) * 32 + (lane & 15);
#pragma unroll
    for (int i = 0; i < 4; ++i) {
        ab[i * 32] = acc0[i];
        ab[i * 32 + 16] = acc1[i];
    }
    if (ks == 0) b_partial(w, pb, batch, mblk, t);
}

// ---- Gauss-Seidel: reduce partials, then sequential over r ----
__global__ __launch_bounds__(256) void gs_kernel(const float* __restrict__ win,
                                                 const float* __restrict__ ap,
                                                 const float* __restrict__ pb,
                                                 float* __restrict__ wout) {
    __shared__ float bs[1024];
    int bz = blockIdx.x, t = threadIdx.x;
    int batch = bz >> 3;
    int m = (bz & 7) * 256 + t;
    float4 bacc = {0.f, 0.f, 0.f, 0.f};
    const float* pbb = pb + (size_t)batch * 1024 + t * 4;
#pragma unroll 8
    for (int s = 0; s < 32; ++s) {
        float4 p = *(const float4*)(pbb + (size_t)s * 8192);
        bacc.x += p.x; bacc.y += p.y; bacc.z += p.z; bacc.w += p.w;
    }
    *(float4*)&bs[t * 4] = bacc;
    __syncthreads();

    float uv[32], av[32];
    const float* up = win + ((size_t)batch * 2048 + m) * 32;
#pragma unroll
    for (int q = 0; q < 8; ++q) *(float4*)&uv[q * 4] = *(const float4*)(up + q * 4);
#pragma unroll
    for (int q = 0; q < 8; ++q) {
        float4 sacc = {0.f, 0.f, 0.f, 0.f};
#pragma unroll
        for (int ks = 0; ks < KSPLIT; ++ks) {
            float4 p = *(const float4*)(ap + (((size_t)ks * 8 + batch) * 2048 + m) * 32 + q * 4);
            sacc.x += p.x; sacc.y += p.y; sacc.z += p.z; sacc.w += p.w;
        }
        *(float4*)&av[q * 4] = sacc;
    }
#pragma unroll
    for (int r = 0; r < 32; ++r) {
        float brr = bs[r * 32 + r];
        float t2 = -uv[r] * brr;
#pragma unroll
        for (int k = 0; k < 32; ++k) t2 = fmaf(uv[k], bs[r * 32 + k], t2);
        float num = av[r] - t2;
        float mag = fmaxf(fabsf(num) - L1REG, 0.f);
        num = copysignf(mag, num);
        uv[r] = (num + 1e-16f) / (brr + L2REG + 1e-16f);
    }
    float* op = wout + ((size_t)batch * 2048 + m) * 32;
#pragma unroll
    for (int q = 0; q < 8; ++q) *(float4*)(op + q * 4) = *(const float4*)&uv[q * 4];
}

extern "C" void kernel_launch(void* const* d_in, const int* in_sizes, int n_in,
                              void* d_out, int out_size, void* d_ws, size_t ws_size,
                              hipStream_t stream) {
    const float* x = (const float*)d_in[0];
    const float* u = (const float*)d_in[1];
    const float* v = (const float*)d_in[2];
    float* out_u = (float*)d_out;
    float* out_v = out_u + (size_t)8 * 2048 * 32;
    float* ap = (float*)d_ws;                          // [4][8][2048][32] f32 = 8 MB
    float* pb = ap + (size_t)KSPLIT * 8 * 2048 * 32;   // [32][8][32][32]  f32 = 1 MB

    // ---- factor 0: update u ----
    gemm_kernel<false><<<1024, 256, 0, stream>>>(x, v, ap, pb);   // a1 = x@v, b1
    gs_kernel<<<64, 256, 0, stream>>>(u, ap, pb, out_u);          // u_new
    // ---- factor 1: update v ----
    gemm_kernel<true><<<1024, 256, 0, stream>>>(x, out_u, ap, pb);  // a2 = x^T@u_new, b2
    gs_kernel<<<64, 256, 0, stream>>>(v, ap, pb, out_v);            // v_new
}